// Round 2
// baseline (2901.742 us; speedup 1.0000x reference)
//
#include <hip/hip_runtime.h>

typedef unsigned short u16;
typedef unsigned int u32;
typedef __attribute__((ext_vector_type(8))) short short8;
typedef __attribute__((ext_vector_type(4))) float f32x4;

// ---------------- helpers ----------------
__device__ inline float bf2f(u16 u) {
    union { u32 i; float f; } v; v.i = ((u32)u) << 16; return v.f;
}
__device__ inline u16 f2b(float f) {
    union { float f; u32 i; } v; v.f = f;
    u32 r = v.i + 0x7fffu + ((v.i >> 16) & 1u);   // round-to-nearest-even
    return (u16)(r >> 16);
}
__device__ inline float fsigm(float x) { return 1.f / (1.f + __expf(-x)); }
__device__ inline float ftanh(float x) {
    x = fminf(fmaxf(x, -20.f), 20.f);   // __expf(2x) overflows past x~44 -> NaN
    float e = __expf(2.f * x);
    return (e - 1.f) / (e + 1.f);
}

// ---------------- setup kernels ----------------

// features [32][196][2048] f32 -> bf16 copy + mean over N (bf16)
__global__ void k_featcast(const float* __restrict__ f, u16* __restrict__ fb,
                           u16* __restrict__ meanb) {
    int blk = blockIdx.x;             // 32*8
    int b = blk >> 3, s = blk & 7;
    int d = s * 256 + threadIdx.x;
    const float* p = f + (size_t)b * 196 * 2048 + d;
    u16* q = fb + (size_t)b * 196 * 2048 + d;
    float sum = 0.f;
    for (int n = 0; n < 196; n++) {
        float v = p[(size_t)n * 2048];
        sum += v;
        q[(size_t)n * 2048] = f2b(v);
    }
    meanb[b * 2048 + d] = f2b(sum * (1.f / 196.f));
}

// generic f32->bf16 cast with optional K-concat of two sources and optional
// gate-permutation of rows (for fused LSTM cell epilogue).
// dst row n' <- src row (g*1024 + (n'/64)*16 + (n'%16)), g=(n'%64)/16
__global__ void k_cast2(const float* __restrict__ s1, int K1,
                        const float* __restrict__ s2, int K2,
                        u16* __restrict__ dst, int rows, int perm) {
    int K = K1 + K2;
    size_t idx = ((size_t)blockIdx.x * 256 + threadIdx.x) * 8;
    size_t total = (size_t)rows * K;
    if (idx >= total) return;
    int n = (int)(idx / K), k = (int)(idx % K);
    int sr = n;
    if (perm) { int g = (n & 63) >> 4; sr = g * 1024 + (n >> 6) * 16 + (n & 15); }
    const float* src = (k < K1) ? (s1 + (size_t)sr * K1 + k)
                                : (s2 + (size_t)sr * K2 + (k - K1));
    u16* d = dst + idx;
#pragma unroll
    for (int j = 0; j < 8; j++) d[j] = f2b(src[j]);
}

// embs_bf16 [T][B][512] = emb[captions[b][t]]
__global__ void k_emb(const int* __restrict__ cap, const float* __restrict__ emb,
                      u16* __restrict__ out) {
    int idx = blockIdx.x * 256 + threadIdx.x;      // 20*32*512
    int k = idx & 511, bt = idx >> 9;
    int t = bt >> 5, b = bt & 31;                  // bt = t*32+b
    out[idx] = f2b(emb[(size_t)cap[b * 20 + t] * 512 + k]);
}

// bias prep: binit_cat[4096], bsum0p/bsum1p (gate-permuted bih+bhh)
__global__ void k_bias(const float* __restrict__ bh, const float* __restrict__ bc,
                       const float* __restrict__ bih0, const float* __restrict__ bhh0,
                       const float* __restrict__ bih1, const float* __restrict__ bhh1,
                       float* __restrict__ binit, float* __restrict__ bs0,
                       float* __restrict__ bs1) {
    int n = blockIdx.x * 256 + threadIdx.x;        // 4096
    binit[n] = (n < 2048) ? bh[n] : bc[n - 2048];
    int g = (n & 63) >> 4, sr = g * 1024 + (n >> 6) * 16 + (n & 15);
    bs0[n] = bih0[sr] + bhh0[sr];
    bs1[n] = bih1[sr] + bhh1[sr];
}

// undo the (L,B,H) flat-view of the [32][4096] init GEMM output
__global__ void k_unview(const float* __restrict__ hc, u16* __restrict__ x1,
                         u16* __restrict__ h1n, float* __restrict__ c0,
                         float* __restrict__ c1) {
    int idx = blockIdx.x * 256 + threadIdx.x;      // 32*4096
    int bp = idx >> 12, col = idx & 4095;
    float v = hc[idx];
    int cc = (col < 2048) ? col : (col - 2048);
    int flat = bp * 2048 + cc;
    int l = flat >> 15, r = flat & 32767, b = r >> 10, h = r & 1023;
    if (col < 2048) {
        if (l == 0) x1[b * 2048 + h] = f2b(v);     // h0 -> x1[:,0:1024)
        else        h1n[b * 1024 + h] = f2b(v);    // h1 -> h1_next
    } else {
        (l == 0 ? c0 : c1)[b * 1024 + h] = v;
    }
}

// ---------------- MFMA GEMMs (B stored row-major [N][K] = B^T) ----------------

// 128x128 tile, BK=32, 4 waves (2x2), wave tile 64x64. M,N multiples of 128.
__global__ __launch_bounds__(256) void gemm128_bt(
    const u16* __restrict__ A, int K, const u16* __restrict__ B,
    const float* __restrict__ bias, float* __restrict__ C, int N) {
    __shared__ short As[128 * 32];
    __shared__ short Bs[128 * 32];
    int tid = threadIdx.x;
    int m0 = blockIdx.x * 128, n0 = blockIdx.y * 128;
    int w = tid >> 6, lane = tid & 63, ln = lane & 15, kg = lane >> 4;
    int wm = w >> 1, wn = w & 1;
    int r = tid >> 2, cb = (tid & 3) * 8;
    f32x4 acc[4][4] = {};
    for (int k0 = 0; k0 < K; k0 += 32) {
        short8 ra0 = *(const short8*)(A + (size_t)(m0 + r) * K + k0 + cb);
        short8 ra1 = *(const short8*)(A + (size_t)(m0 + 64 + r) * K + k0 + cb);
        short8 rb0 = *(const short8*)(B + (size_t)(n0 + r) * K + k0 + cb);
        short8 rb1 = *(const short8*)(B + (size_t)(n0 + 64 + r) * K + k0 + cb);
        __syncthreads();
        *(short8*)&As[tid * 8] = ra0;
        *(short8*)&As[2048 + tid * 8] = ra1;
        *(short8*)&Bs[tid * 8] = rb0;
        *(short8*)&Bs[2048 + tid * 8] = rb1;
        __syncthreads();
        short8 af[4], bfr[4];
#pragma unroll
        for (int i = 0; i < 4; i++) {
            af[i]  = *(const short8*)&As[(wm * 64 + i * 16 + ln) * 32 + kg * 8];
            bfr[i] = *(const short8*)&Bs[(wn * 64 + i * 16 + ln) * 32 + kg * 8];
        }
#pragma unroll
        for (int mf = 0; mf < 4; mf++)
#pragma unroll
            for (int nf = 0; nf < 4; nf++)
                acc[mf][nf] = __builtin_amdgcn_mfma_f32_16x16x32_bf16(
                    af[mf], bfr[nf], acc[mf][nf], 0, 0, 0);
    }
    int rowb = m0 + wm * 64, colb = n0 + wn * 64;
#pragma unroll
    for (int mf = 0; mf < 4; mf++)
#pragma unroll
        for (int nf = 0; nf < 4; nf++) {
            int col = colb + nf * 16 + ln;
            float bv = bias ? bias[col] : 0.f;
#pragma unroll
            for (int j = 0; j < 4; j++) {
                int row = rowb + mf * 16 + kg * 4 + j;
                C[(size_t)row * N + col] = acc[mf][nf][j] + bv;
            }
        }
}

// M=32 specialized: tile 32x(64), BK=64, 4 waves each own 16 N-cols.
// FUSE=1: gate-permuted B; epilogue does the LSTM cell in-block.
template <int FUSE>
__global__ __launch_bounds__(256) void gemm32_bt(
    const u16* __restrict__ A, int lda, int K, const u16* __restrict__ B,
    const float* __restrict__ bias, float* __restrict__ C, int N,
    float* __restrict__ c_state, u16* __restrict__ hA, int sA,
    u16* __restrict__ hB, int sB) {
    __shared__ short As[32 * 64];
    __shared__ short Bs[64 * 64];
    __shared__ float gs[FUSE ? 32 * 64 : 1];
    int tid = threadIdx.x;
    int n0 = blockIdx.x * 64;
    int w = tid >> 6, lane = tid & 63, ln = lane & 15, kg = lane >> 4;
    int r = tid >> 3, cb = (tid & 7) * 8;
    f32x4 acc[2] = {};
    for (int k0 = 0; k0 < K; k0 += 64) {
        short8 ra  = *(const short8*)(A + (size_t)r * lda + k0 + cb);
        short8 rb0 = *(const short8*)(B + (size_t)(n0 + r) * K + k0 + cb);
        short8 rb1 = *(const short8*)(B + (size_t)(n0 + 32 + r) * K + k0 + cb);
        __syncthreads();
        *(short8*)&As[tid * 8] = ra;
        *(short8*)&Bs[tid * 8] = rb0;
        *(short8*)&Bs[2048 + tid * 8] = rb1;
        __syncthreads();
#pragma unroll
        for (int ks = 0; ks < 2; ks++) {
            short8 bfrag = *(const short8*)&Bs[(w * 16 + ln) * 64 + ks * 32 + kg * 8];
#pragma unroll
            for (int mf = 0; mf < 2; mf++) {
                short8 afrag = *(const short8*)&As[(mf * 16 + ln) * 64 + ks * 32 + kg * 8];
                acc[mf] = __builtin_amdgcn_mfma_f32_16x16x32_bf16(
                    afrag, bfrag, acc[mf], 0, 0, 0);
            }
        }
    }
    if (FUSE == 0) {
        int col = n0 + w * 16 + ln;
        float bv = bias ? bias[col] : 0.f;
#pragma unroll
        for (int mf = 0; mf < 2; mf++)
#pragma unroll
            for (int j = 0; j < 4; j++) {
                int row = mf * 16 + kg * 4 + j;
                C[(size_t)row * N + col] = acc[mf][j] + bv;
            }
    } else {
        int colc = w * 16 + ln;
        float bv = bias[n0 + colc];
#pragma unroll
        for (int mf = 0; mf < 2; mf++)
#pragma unroll
            for (int j = 0; j < 4; j++)
                gs[(mf * 16 + kg * 4 + j) * 64 + colc] = acc[mf][j] + bv;
        __syncthreads();
#pragma unroll
        for (int rep = 0; rep < 2; rep++) {
            int idx = rep * 256 + tid;             // 0..511: 32 b x 16 jj
            int b = idx >> 4, jj = idx & 15;
            int j = (n0 >> 2) + jj;                // (n0/64)*16 + jj
            float iv = gs[b * 64 + jj];
            float fv = gs[b * 64 + 16 + jj];
            float gv = gs[b * 64 + 32 + jj];
            float ov = gs[b * 64 + 48 + jj];
            float co = c_state[b * 1024 + j];
            float cn = fsigm(fv) * co + fsigm(iv) * ftanh(gv);
            float hn = fsigm(ov) * ftanh(cn);
            c_state[b * 1024 + j] = cn;
            u16 hb = f2b(hn);
            hA[b * sA + j] = hb;
            if (hB) hB[b * sB + j] = hb;
        }
    }
}

// ---------------- per-step kernels ----------------

// one block per batch b: state routing copies + a2 + scores + softmax
__global__ void k_att(const u16* __restrict__ embst,   // embs_bf16 + t*32*512
                      const u16* __restrict__ x1,      // [32][2048] (h0 in [0:1024))
                      const u16* __restrict__ h1n,     // [32][1024]
                      u16* __restrict__ x0,            // [32][3584]
                      u16* __restrict__ x1w,           // x1 (write h1 half)
                      const u16* __restrict__ Ua,      // bf16 [256][1024]
                      const float* __restrict__ bu, const float* __restrict__ va,
                      const float* __restrict__ a1, float* __restrict__ wbuf) {
    int b = blockIdx.x, tid = threadIdx.x;
    __shared__ float h0f[1024];
    __shared__ float a2s[256];
    __shared__ float red[256];
    // emb -> x0[:,0:512)
    { const u32* s = (const u32*)(embst + b * 512);
      u32* d = (u32*)(x0 + (size_t)b * 3584);
      d[tid] = s[tid]; }                                 // 256 u32 = 512 bf16
    // h0: x1[:,0:1024) -> x0[:,2560:3584) and LDS f32
    { const u32* s = (const u32*)(x1 + b * 2048);
      u32* d = (u32*)(x0 + (size_t)b * 3584 + 2560);
      u32 u0 = s[tid], u1 = s[tid + 256];
      d[tid] = u0; d[tid + 256] = u1;
      h0f[tid * 2] = bf2f((u16)(u0 & 0xffff));
      h0f[tid * 2 + 1] = bf2f((u16)(u0 >> 16));
      h0f[512 + tid * 2] = bf2f((u16)(u1 & 0xffff));
      h0f[512 + tid * 2 + 1] = bf2f((u16)(u1 >> 16)); }
    // h1_next -> x1[:,1024:2048)
    { const u32* s = (const u32*)(h1n + b * 1024);
      u32* d = (u32*)(x1w + b * 2048 + 1024);
      d[tid] = s[tid]; d[tid + 256] = s[tid + 256]; }
    __syncthreads();
    // a2[a] = h0 . Ua[a] + bu[a]
    {
        const u16* ur = Ua + (size_t)tid * 1024;
        float acc = 0.f;
        for (int k = 0; k < 1024; k += 8) {
            short8 uv = *(const short8*)(ur + k);
#pragma unroll
            for (int j = 0; j < 8; j++)
                acc = fmaf(bf2f((u16)uv[j]), h0f[k + j], acc);
        }
        a2s[tid] = acc + bu[tid];
    }
    __syncthreads();
    // scores + softmax over n=0..195
    float sres = -1e30f;
    if (tid < 196) {
        const float* ar = a1 + ((size_t)(b * 196 + tid)) * 256;
        float acc = 0.f;
        for (int k = 0; k < 256; k++)
            acc = fmaf(va[k], ftanh(ar[k] + a2s[k]), acc);
        sres = acc;
    }
    red[tid] = sres;
    __syncthreads();
    for (int off = 128; off > 0; off >>= 1) {
        if (tid < off) red[tid] = fmaxf(red[tid], red[tid + off]);
        __syncthreads();
    }
    float mx = red[0];
    __syncthreads();
    float e = (tid < 196) ? __expf(sres - mx) : 0.f;
    red[tid] = e;
    __syncthreads();
    for (int off = 128; off > 0; off >>= 1) {
        if (tid < off) red[tid] += red[tid + off];
        __syncthreads();
    }
    float inv = 1.f / red[0];
    if (tid < 196) wbuf[b * 196 + tid] = e * inv;
}

// ctx: 256 blocks = 32 b x 8 d-slices; ctx -> x0[:,512:2560) bf16
__global__ void k_ctx(const float* __restrict__ w, const u16* __restrict__ fb,
                      u16* __restrict__ x0) {
    int blk = blockIdx.x;
    int b = blk >> 3, s = blk & 7;
    int d = s * 256 + threadIdx.x;
    __shared__ float wl[196];
    if (threadIdx.x < 196) wl[threadIdx.x] = w[b * 196 + threadIdx.x];
    __syncthreads();
    const u16* fp = fb + (size_t)b * 196 * 2048 + d;
    float acc = 0.f;
#pragma unroll 4
    for (int n = 0; n < 196; n++)
        acc = fmaf(wl[n], bf2f(fp[(size_t)n * 2048]), acc);
    x0[(size_t)b * 3584 + 512 + d] = f2b(acc);
}

// ---------------- launcher ----------------
extern "C" void kernel_launch(void* const* d_in, const int* in_sizes, int n_in,
                              void* d_out, int out_size, void* d_ws, size_t ws_size,
                              hipStream_t stream) {
    const float* features = (const float*)d_in[0];
    const int*   captions = (const int*)d_in[1];
    const float* emb   = (const float*)d_in[2];
    const float* Wa    = (const float*)d_in[3];
    const float* ba    = (const float*)d_in[4];
    const float* Ua    = (const float*)d_in[5];
    const float* bu    = (const float*)d_in[6];
    const float* va    = (const float*)d_in[7];
    const float* Wh_init = (const float*)d_in[9];
    const float* bh_init = (const float*)d_in[10];
    const float* Wc_init = (const float*)d_in[11];
    const float* bc_init = (const float*)d_in[12];
    const float* Wih0 = (const float*)d_in[13];
    const float* Whh0 = (const float*)d_in[14];
    const float* bih0 = (const float*)d_in[15];
    const float* bhh0 = (const float*)d_in[16];
    const float* Wih1 = (const float*)d_in[17];
    const float* Whh1 = (const float*)d_in[18];
    const float* bih1 = (const float*)d_in[19];
    const float* bhh1 = (const float*)d_in[20];
    const float* Wfc  = (const float*)d_in[21];
    const float* bfc  = (const float*)d_in[22];
    float* out = (float*)d_out;

    char* p = (char*)d_ws;
    auto alloc = [&](size_t bytes) -> char* {
        char* q = p; p += (bytes + 255) & ~(size_t)255; return q;
    };
    u16* feat_b  = (u16*)alloc((size_t)32 * 196 * 2048 * 2);
    u16* Wfc_b   = (u16*)alloc((size_t)32000 * 1024 * 2);
    u16* Wcat0   = (u16*)alloc((size_t)4096 * 3584 * 2);
    u16* Wcat1   = (u16*)alloc((size_t)4096 * 2048 * 2);
    u16* Winit_b = (u16*)alloc((size_t)4096 * 2048 * 2);
    u16* Wa_b    = (u16*)alloc((size_t)256 * 2048 * 2);
    u16* Ua_b    = (u16*)alloc((size_t)256 * 1024 * 2);
    u16* mean_b  = (u16*)alloc((size_t)32 * 2048 * 2);
    u16* embs_b  = (u16*)alloc((size_t)20 * 32 * 512 * 2);
    float* a1buf = (float*)alloc((size_t)32 * 196 * 256 * 4);
    float* hc    = (float*)alloc((size_t)32 * 4096 * 4);
    u16* x0      = (u16*)alloc((size_t)32 * 3584 * 2);
    u16* x1      = (u16*)alloc((size_t)32 * 2048 * 2);
    float* c0    = (float*)alloc((size_t)32 * 1024 * 4);
    float* c1    = (float*)alloc((size_t)32 * 1024 * 4);
    u16* h1n     = (u16*)alloc((size_t)32 * 1024 * 2);
    float* wbuf  = (float*)alloc((size_t)32 * 196 * 4);
    u16* outs_b  = (u16*)alloc((size_t)640 * 1024 * 2);
    float* binit = (float*)alloc(4096 * 4);
    float* bs0   = (float*)alloc(4096 * 4);
    float* bs1   = (float*)alloc(4096 * 4);

    // setup
    k_featcast<<<256, 256, 0, stream>>>(features, feat_b, mean_b);
    k_cast2<<<256, 256, 0, stream>>>(Wa, 2048, nullptr, 0, Wa_b, 256, 0);
    k_cast2<<<128, 256, 0, stream>>>(Ua, 1024, nullptr, 0, Ua_b, 256, 0);
    k_cast2<<<16000, 256, 0, stream>>>(Wfc, 1024, nullptr, 0, Wfc_b, 32000, 0);
    k_cast2<<<7168, 256, 0, stream>>>(Wih0, 2560, Whh0, 1024, Wcat0, 4096, 1);
    k_cast2<<<4096, 256, 0, stream>>>(Wih1, 1024, Whh1, 1024, Wcat1, 4096, 1);
    k_cast2<<<2048, 256, 0, stream>>>(Wh_init, 2048, nullptr, 0, Winit_b, 2048, 0);
    k_cast2<<<2048, 256, 0, stream>>>(Wc_init, 2048, nullptr, 0,
                                      Winit_b + (size_t)2048 * 2048, 2048, 0);
    k_emb<<<1280, 256, 0, stream>>>(captions, emb, embs_b);
    k_bias<<<16, 256, 0, stream>>>(bh_init, bc_init, bih0, bhh0, bih1, bhh1,
                                   binit, bs0, bs1);
    // a1 = features @ Wa^T + ba   [6272 x 256]
    { dim3 g(49, 2); gemm128_bt<<<g, 256, 0, stream>>>(feat_b, 2048, Wa_b, ba,
                                                       a1buf, 256); }
    // init h/c = mean @ [Wh;Wc]^T + b  [32 x 4096]
    gemm32_bt<0><<<64, 256, 0, stream>>>(mean_b, 2048, 2048, Winit_b, binit,
                                         hc, 4096, nullptr, nullptr, 0, nullptr, 0);
    k_unview<<<512, 256, 0, stream>>>(hc, x1, h1n, c0, c1);

    // recurrence
    for (int t = 0; t < 20; t++) {
        k_att<<<32, 256, 0, stream>>>(embs_b + (size_t)t * 32 * 512, x1, h1n,
                                      x0, x1, Ua_b, bu, va, a1buf, wbuf);
        k_ctx<<<256, 256, 0, stream>>>(wbuf, feat_b, x0);
        // LSTM0: gates+cell fused; h0' -> x1[:,0:1024)
        gemm32_bt<1><<<64, 256, 0, stream>>>(x0, 3584, 3584, Wcat0, bs0,
                                             nullptr, 4096, c0,
                                             x1, 2048, nullptr, 0);
        // LSTM1: h1' -> h1_next and outs_bf16 row (b*20+t)
        gemm32_bt<1><<<64, 256, 0, stream>>>(x1, 2048, 2048, Wcat1, bs1,
                                             nullptr, 4096, c1,
                                             h1n, 1024, outs_b + (size_t)t * 1024,
                                             20 * 1024);
    }

    // logits = outs @ Wfc^T + bfc   [640 x 32000]
    { dim3 g(5, 250); gemm128_bt<<<g, 256, 0, stream>>>(outs_b, 1024, Wfc_b, bfc,
                                                        out, 32000); }
}